// Round 1
// baseline (192.965 us; speedup 1.0000x reference)
//
#include <hip/hip_runtime.h>

typedef __attribute__((ext_vector_type(8))) short bf16x8;
typedef __attribute__((ext_vector_type(4))) float f32x4;
typedef __attribute__((ext_vector_type(4))) unsigned short us4;

#define LOG2E 1.44269504088896f

__device__ inline unsigned short f2bf(float f) {
    unsigned u = __float_as_uint(f);
    u += 0x7fffu + ((u >> 16) & 1u);
    return (unsigned short)(u >> 16);
}

// ---------------- fp32 -> bf16 convert (n % 4 == 0) ----------------
__global__ void cvt_kernel(const float* __restrict__ src, unsigned short* __restrict__ dst, int n) {
    int i = (blockIdx.x * blockDim.x + threadIdx.x) * 4;
    const int stride = gridDim.x * blockDim.x * 4;
    for (; i < n; i += stride) {
        const float4 v = *reinterpret_cast<const float4*>(src + i);
        us4 o;
        o.x = f2bf(v.x); o.y = f2bf(v.y); o.z = f2bf(v.z); o.w = f2bf(v.w);
        *reinterpret_cast<us4*>(dst + i) = o;
    }
}

// ---------------- shared GEMM mainloop ----------------
// A [M][1024] bf16 row-major, Bw [Ncols][1024] bf16 row-major (i.e. computes A.Bw^T).
// 128x128 tile, 4 waves in 2x2, each wave 64x64 (4x4 fragments of 16x16x32 MFMA).
__device__ inline void gemm_mainloop(const unsigned short* __restrict__ A,
                                     const unsigned short* __restrict__ Bw,
                                     unsigned short* As, unsigned short* Bs,
                                     int tm, int tn, f32x4 (&acc)[4][4]) {
    const int K = 1024;
    const int tid = threadIdx.x;
    const int lane = tid & 63;
    const int wv = tid >> 6;
    const int wr = wv >> 1, wc = wv & 1;
    const int lr = lane & 15, lk = (lane >> 4) * 8;

    const unsigned short* Ag = A + (size_t)(tm * 128 + (tid >> 2)) * K + (tid & 3) * 8;
    const unsigned short* Bg = Bw + (size_t)(tn * 128 + (tid >> 2)) * K + (tid & 3) * 8;
    unsigned short* AsD = As + tid * 8;
    unsigned short* BsD = Bs + tid * 8;

    for (int k0 = 0; k0 < K; k0 += 32) {
        __builtin_amdgcn_global_load_lds((const __attribute__((address_space(1))) void*)(Ag + k0),
                                         (__attribute__((address_space(3))) void*)AsD, 16, 0, 0);
        __builtin_amdgcn_global_load_lds((const __attribute__((address_space(1))) void*)(Ag + 64 * K + k0),
                                         (__attribute__((address_space(3))) void*)(AsD + 2048), 16, 0, 0);
        __builtin_amdgcn_global_load_lds((const __attribute__((address_space(1))) void*)(Bg + k0),
                                         (__attribute__((address_space(3))) void*)BsD, 16, 0, 0);
        __builtin_amdgcn_global_load_lds((const __attribute__((address_space(1))) void*)(Bg + 64 * K + k0),
                                         (__attribute__((address_space(3))) void*)(BsD + 2048), 16, 0, 0);
        __syncthreads();
        bf16x8 af[4], bfv[4];
#pragma unroll
        for (int i = 0; i < 4; i++) {
            af[i]  = *reinterpret_cast<const bf16x8*>(As + (wr * 64 + i * 16 + lr) * 32 + lk);
            bfv[i] = *reinterpret_cast<const bf16x8*>(Bs + (wc * 64 + i * 16 + lr) * 32 + lk);
        }
#pragma unroll
        for (int i = 0; i < 4; i++)
#pragma unroll
            for (int j = 0; j < 4; j++)
                acc[i][j] = __builtin_amdgcn_mfma_f32_16x16x32_bf16(af[i], bfv[j], acc[i][j], 0, 0, 0);
        __syncthreads();
    }
}

// ---------------- GEMM1: qkv = x @ qkv_w^T + b, RoPE on q,k, scatter ----------------
__global__ __launch_bounds__(256) void gemm_qkv_kernel(
        const unsigned short* __restrict__ A, const unsigned short* __restrict__ Bw,
        const float* __restrict__ bias, const float* __restrict__ cosT, const float* __restrict__ sinT,
        unsigned short* __restrict__ Qb, unsigned short* __restrict__ Kb, unsigned short* __restrict__ Vt) {
    __shared__ __align__(16) unsigned short As[128 * 32];
    __shared__ __align__(16) unsigned short Bs[128 * 32];
    const int tid = threadIdx.x;
    const int lane = tid & 63;
    const int wv = tid >> 6;
    const int wr = wv >> 1, wc = wv & 1;
    const int tm = blockIdx.y, tn = blockIdx.x;
    const int lr = lane & 15;

    f32x4 acc[4][4];
#pragma unroll
    for (int i = 0; i < 4; i++)
#pragma unroll
        for (int j = 0; j < 4; j++)
#pragma unroll
            for (int q = 0; q < 4; q++) acc[i][j][q] = 0.f;

    gemm_mainloop(A, Bw, As, Bs, tm, tn, acc);

    // epilogue: col c = tn*128 + wc*64 + j*16 + lr ; row m = tm*128 + wr*64 + i*16 + (lane>>4)*4 + r
    const int cbase = tn * 128 + wc * 64;          // multiple of 64, head-aligned
    const int sec = cbase >> 10;                   // 0=q 1=k 2=v
    const int h = (cbase & 1023) >> 6;
    float bias_c[4];
#pragma unroll
    for (int j = 0; j < 4; j++) bias_c[j] = bias[cbase + j * 16 + lr];

#pragma unroll
    for (int i = 0; i < 4; i++) {
#pragma unroll
        for (int r = 0; r < 4; r++) {
            const int m = tm * 128 + wr * 64 + i * 16 + (lane >> 4) * 4 + r;
            const int b = m >> 10, n = m & 1023;
            float vals[4];
#pragma unroll
            for (int j = 0; j < 4; j++) vals[j] = acc[i][j][r] + bias_c[j];
            if (sec == 2) {
#pragma unroll
                for (int j = 0; j < 4; j++) {
                    const int d = j * 16 + lr;
                    Vt[((size_t)((b * 16 + h) * 64 + d)) * 1024 + n] = f2bf(vals[j]);
                }
            } else {
#pragma unroll
                for (int j = 0; j < 4; j++) {
                    const int d = j * 16 + lr;
                    const float c = cosT[n * 64 + d];
                    const float s = sinT[n * 64 + d];
                    const float pr = vals[j ^ 2];          // paired element d ^ 32
                    float outv = vals[j] * c + (d < 32 ? -pr : pr) * s;
                    if (sec == 0) outv *= 0.125f;          // fold attn scale into Q
                    unsigned short* dst = (sec == 0) ? Qb : Kb;
                    dst[((size_t)((b * 16 + h) * 1024 + n)) * 64 + d] = f2bf(outv);
                }
            }
        }
    }
}

// ---------------- flash attention ----------------
// grid (8 q-tiles, 64 bh); 4 waves/block, wave handles 32 q rows.
__global__ __launch_bounds__(256) void attn_kernel(
        const unsigned short* __restrict__ Qb, const unsigned short* __restrict__ Kb,
        const unsigned short* __restrict__ Vt, unsigned short* __restrict__ AO) {
    __shared__ __align__(16) unsigned short Pbuf[4][32 * 64];
    const int tid = threadIdx.x, lane = tid & 63, wv = tid >> 6;
    const int bh = blockIdx.y, qt = blockIdx.x;
    const int qbase = qt * 128 + wv * 32;
    const unsigned short* Qp = Qb + (size_t)bh * 65536;
    const unsigned short* Kp = Kb + (size_t)bh * 65536;
    const unsigned short* Vp = Vt + (size_t)bh * 65536;
    const int lr = lane & 15, lg = lane >> 4;

    bf16x8 qf[2][2];
#pragma unroll
    for (int rb = 0; rb < 2; rb++)
#pragma unroll
        for (int kc = 0; kc < 2; kc++)
            qf[rb][kc] = *reinterpret_cast<const bf16x8*>(Qp + (qbase + rb * 16 + lr) * 64 + kc * 32 + lg * 8);

    f32x4 o[2][4];
    float mrow[2][4], lrow[2][4];
#pragma unroll
    for (int rb = 0; rb < 2; rb++) {
#pragma unroll
        for (int cf = 0; cf < 4; cf++)
#pragma unroll
            for (int q = 0; q < 4; q++) o[rb][cf][q] = 0.f;
#pragma unroll
        for (int r = 0; r < 4; r++) { mrow[rb][r] = -1e30f; lrow[rb][r] = 0.f; }
    }

    char* Pw = (char*)&Pbuf[wv][0];

    for (int kt = 0; kt < 1024; kt += 64) {
        f32x4 s[2][4];
#pragma unroll
        for (int rb = 0; rb < 2; rb++)
#pragma unroll
            for (int cf = 0; cf < 4; cf++)
#pragma unroll
                for (int q = 0; q < 4; q++) s[rb][cf][q] = 0.f;

#pragma unroll
        for (int kc = 0; kc < 2; kc++) {
#pragma unroll
            for (int cf = 0; cf < 4; cf++) {
                const bf16x8 kf = *reinterpret_cast<const bf16x8*>(Kp + (kt + cf * 16 + lr) * 64 + kc * 32 + lg * 8);
                s[0][cf] = __builtin_amdgcn_mfma_f32_16x16x32_bf16(qf[0][kc], kf, s[0][cf], 0, 0, 0);
                s[1][cf] = __builtin_amdgcn_mfma_f32_16x16x32_bf16(qf[1][kc], kf, s[1][cf], 0, 0, 0);
            }
        }
        // online softmax per q-row (row = rb*16 + lg*4 + r, cols across lane&15)
#pragma unroll
        for (int rb = 0; rb < 2; rb++) {
#pragma unroll
            for (int r = 0; r < 4; r++) {
                float mx = fmaxf(fmaxf(s[rb][0][r], s[rb][1][r]), fmaxf(s[rb][2][r], s[rb][3][r]));
#pragma unroll
                for (int msk = 1; msk < 16; msk <<= 1) mx = fmaxf(mx, __shfl_xor(mx, msk, 64));
                const float mold = mrow[rb][r];
                const float mnew = fmaxf(mold, mx);
                const float fsc = exp2f((mold - mnew) * LOG2E);
                mrow[rb][r] = mnew;
                float rs = 0.f;
#pragma unroll
                for (int cf = 0; cf < 4; cf++) {
                    const float p = exp2f((s[rb][cf][r] - mnew) * LOG2E);
                    s[rb][cf][r] = p;
                    rs += p;
                }
#pragma unroll
                for (int msk = 1; msk < 16; msk <<= 1) rs += __shfl_xor(rs, msk, 64);
                lrow[rb][r] = lrow[rb][r] * fsc + rs;
#pragma unroll
                for (int cf = 0; cf < 4; cf++) o[rb][cf][r] *= fsc;
            }
        }
        // P (C/D layout) -> LDS bf16, XOR-swizzled rows
#pragma unroll
        for (int rb = 0; rb < 2; rb++)
#pragma unroll
            for (int r = 0; r < 4; r++) {
                const int prow = rb * 16 + lg * 4 + r;
#pragma unroll
                for (int cf = 0; cf < 4; cf++) {
                    const int boff = (prow * 128 + (cf * 16 + lr) * 2) ^ ((prow & 7) << 4);
                    *reinterpret_cast<unsigned short*>(Pw + boff) = f2bf(s[rb][cf][r]);
                }
            }
        asm volatile("s_waitcnt lgkmcnt(0)" ::: "memory");
        // PV: A = P rows (from LDS), B = V cols (Vt contiguous)
#pragma unroll
        for (int kc = 0; kc < 2; kc++) {
            bf16x8 pf[2];
#pragma unroll
            for (int rb = 0; rb < 2; rb++) {
                const int prow = rb * 16 + lr;
                const int boff = (prow * 128 + (kc * 32 + lg * 8) * 2) ^ ((prow & 7) << 4);
                pf[rb] = *reinterpret_cast<const bf16x8*>(Pw + boff);
            }
#pragma unroll
            for (int cf = 0; cf < 4; cf++) {
                const bf16x8 vf = *reinterpret_cast<const bf16x8*>(Vp + (cf * 16 + lr) * 1024 + kt + kc * 32 + lg * 8);
                o[0][cf] = __builtin_amdgcn_mfma_f32_16x16x32_bf16(pf[0], vf, o[0][cf], 0, 0, 0);
                o[1][cf] = __builtin_amdgcn_mfma_f32_16x16x32_bf16(pf[1], vf, o[1][cf], 0, 0, 0);
            }
        }
    }
    // epilogue: AO [b][n][h*64+d] bf16
    const int b = bh >> 4, h = bh & 15;
#pragma unroll
    for (int rb = 0; rb < 2; rb++)
#pragma unroll
        for (int cf = 0; cf < 4; cf++)
#pragma unroll
            for (int r = 0; r < 4; r++) {
                const int n = qbase + rb * 16 + lg * 4 + r;
                AO[(size_t)(b * 1024 + n) * 1024 + h * 64 + cf * 16 + lr] = f2bf(o[rb][cf][r] / lrow[rb][r]);
            }
}

// ---------------- GEMM2: out = AO @ proj_w^T + proj_b (fp32 out) ----------------
__global__ __launch_bounds__(256) void gemm_proj_kernel(
        const unsigned short* __restrict__ A, const unsigned short* __restrict__ Bw,
        const float* __restrict__ bias, float* __restrict__ out) {
    __shared__ __align__(16) unsigned short As[128 * 32];
    __shared__ __align__(16) unsigned short Bs[128 * 32];
    const int tid = threadIdx.x;
    const int lane = tid & 63;
    const int wv = tid >> 6;
    const int wr = wv >> 1, wc = wv & 1;
    const int tm = blockIdx.y, tn = blockIdx.x;
    const int lr = lane & 15;

    f32x4 acc[4][4];
#pragma unroll
    for (int i = 0; i < 4; i++)
#pragma unroll
        for (int j = 0; j < 4; j++)
#pragma unroll
            for (int q = 0; q < 4; q++) acc[i][j][q] = 0.f;

    gemm_mainloop(A, Bw, As, Bs, tm, tn, acc);

#pragma unroll
    for (int i = 0; i < 4; i++)
#pragma unroll
        for (int j = 0; j < 4; j++)
#pragma unroll
            for (int r = 0; r < 4; r++) {
                const int row = tm * 128 + wr * 64 + i * 16 + (lane >> 4) * 4 + r;
                const int col = tn * 128 + wc * 64 + j * 16 + lr;
                out[(size_t)row * 1024 + col] = acc[i][j][r] + bias[col];
            }
}

extern "C" void kernel_launch(void* const* d_in, const int* in_sizes, int n_in,
                              void* d_out, int out_size, void* d_ws, size_t ws_size,
                              hipStream_t stream) {
    const float* x      = (const float*)d_in[0];
    const float* cosT   = (const float*)d_in[1];
    const float* sinT   = (const float*)d_in[2];
    const float* qkv_w  = (const float*)d_in[3];
    const float* qkv_b  = (const float*)d_in[4];
    const float* proj_w = (const float*)d_in[5];
    const float* proj_b = (const float*)d_in[6];
    float* out = (float*)d_out;

    char* ws = (char*)d_ws;
    unsigned short* xb    = (unsigned short*)(ws);                 // 8 MB  [4096][1024]
    unsigned short* wqkv  = (unsigned short*)(ws + (8u << 20));    // 6 MB  [3072][1024]
    unsigned short* wproj = (unsigned short*)(ws + (14u << 20));   // 2 MB  [1024][1024]
    unsigned short* Qb    = (unsigned short*)(ws + (16u << 20));   // 8 MB  [64][1024][64]
    unsigned short* Kb    = (unsigned short*)(ws + (24u << 20));   // 8 MB  [64][1024][64]
    unsigned short* Vt    = (unsigned short*)(ws + (32u << 20));   // 8 MB  [64][64][1024]
    unsigned short* AO    = (unsigned short*)(ws + (40u << 20));   // 8 MB  [4096][1024]

    cvt_kernel<<<2048, 256, 0, stream>>>(x, xb, 4096 * 1024);
    cvt_kernel<<<2048, 256, 0, stream>>>(qkv_w, wqkv, 3072 * 1024);
    cvt_kernel<<<1024, 256, 0, stream>>>(proj_w, wproj, 1024 * 1024);
    gemm_qkv_kernel<<<dim3(24, 32), 256, 0, stream>>>(xb, wqkv, qkv_b, cosT, sinT, Qb, Kb, Vt);
    attn_kernel<<<dim3(8, 64), 256, 0, stream>>>(Qb, Kb, Vt, AO);
    gemm_proj_kernel<<<dim3(8, 32), 256, 0, stream>>>(AO, wproj, proj_b, out);
}

// Round 2
// 159.953 us; speedup vs baseline: 1.2064x; 1.2064x over previous
//
#include <hip/hip_runtime.h>

typedef __attribute__((ext_vector_type(8))) short bf16x8;
typedef __attribute__((ext_vector_type(4))) float f32x4;
typedef __attribute__((ext_vector_type(4))) unsigned short us4;

#define LOG2E 1.44269504088896f

__device__ inline unsigned short f2bf(float f) {
    unsigned u = __float_as_uint(f);
    u += 0x7fffu + ((u >> 16) & 1u);
    return (unsigned short)(u >> 16);
}

// ---------------- fp32 -> bf16 convert (n % 4 == 0) ----------------
__global__ void cvt_kernel(const float* __restrict__ src, unsigned short* __restrict__ dst, int n) {
    int i = (blockIdx.x * blockDim.x + threadIdx.x) * 4;
    const int stride = gridDim.x * blockDim.x * 4;
    for (; i < n; i += stride) {
        const float4 v = *reinterpret_cast<const float4*>(src + i);
        us4 o;
        o.x = f2bf(v.x); o.y = f2bf(v.y); o.z = f2bf(v.z); o.w = f2bf(v.w);
        *reinterpret_cast<us4*>(dst + i) = o;
    }
}

// ---------------- shared GEMM mainloop ----------------
// A [M][1024] bf16 row-major, Bw [Ncols][1024] bf16 row-major (computes A.Bw^T).
// 128x128 tile, 4 waves in 2x2, each wave 64x64 (4x4 fragments of 16x16x32 MFMA).
__device__ inline void gemm_mainloop(const unsigned short* __restrict__ A,
                                     const unsigned short* __restrict__ Bw,
                                     unsigned short* As, unsigned short* Bs,
                                     int tm, int tn, f32x4 (&acc)[4][4]) {
    const int K = 1024;
    const int tid = threadIdx.x;
    const int lane = tid & 63;
    const int wv = tid >> 6;
    const int wr = wv >> 1, wc = wv & 1;
    const int lr = lane & 15, lk = (lane >> 4) * 8;

    const unsigned short* Ag = A + (size_t)(tm * 128 + (tid >> 2)) * K + (tid & 3) * 8;
    const unsigned short* Bg = Bw + (size_t)(tn * 128 + (tid >> 2)) * K + (tid & 3) * 8;
    unsigned short* AsD = As + tid * 8;
    unsigned short* BsD = Bs + tid * 8;

    for (int k0 = 0; k0 < K; k0 += 32) {
        __builtin_amdgcn_global_load_lds((const __attribute__((address_space(1))) void*)(Ag + k0),
                                         (__attribute__((address_space(3))) void*)AsD, 16, 0, 0);
        __builtin_amdgcn_global_load_lds((const __attribute__((address_space(1))) void*)(Ag + 64 * K + k0),
                                         (__attribute__((address_space(3))) void*)(AsD + 2048), 16, 0, 0);
        __builtin_amdgcn_global_load_lds((const __attribute__((address_space(1))) void*)(Bg + k0),
                                         (__attribute__((address_space(3))) void*)BsD, 16, 0, 0);
        __builtin_amdgcn_global_load_lds((const __attribute__((address_space(1))) void*)(Bg + 64 * K + k0),
                                         (__attribute__((address_space(3))) void*)(BsD + 2048), 16, 0, 0);
        __syncthreads();
        bf16x8 af[4], bfv[4];
#pragma unroll
        for (int i = 0; i < 4; i++) {
            af[i]  = *reinterpret_cast<const bf16x8*>(As + (wr * 64 + i * 16 + lr) * 32 + lk);
            bfv[i] = *reinterpret_cast<const bf16x8*>(Bs + (wc * 64 + i * 16 + lr) * 32 + lk);
        }
#pragma unroll
        for (int i = 0; i < 4; i++)
#pragma unroll
            for (int j = 0; j < 4; j++)
                acc[i][j] = __builtin_amdgcn_mfma_f32_16x16x32_bf16(af[i], bfv[j], acc[i][j], 0, 0, 0);
        __syncthreads();
    }
}

// ---------------- GEMM1: qkv = x @ qkv_w^T + b, RoPE on q,k, scatter ----------------
__global__ __launch_bounds__(256) void gemm_qkv_kernel(
        const unsigned short* __restrict__ A, const unsigned short* __restrict__ Bw,
        const float* __restrict__ bias, const float* __restrict__ cosT, const float* __restrict__ sinT,
        unsigned short* __restrict__ Qb, unsigned short* __restrict__ Kb, unsigned short* __restrict__ Vt) {
    __shared__ __align__(16) unsigned short As[128 * 32];
    __shared__ __align__(16) unsigned short Bs[128 * 32];
    const int tid = threadIdx.x;
    const int lane = tid & 63;
    const int wv = tid >> 6;
    const int wr = wv >> 1, wc = wv & 1;
    const int tm = blockIdx.y, tn = blockIdx.x;
    const int lr = lane & 15;

    f32x4 acc[4][4];
#pragma unroll
    for (int i = 0; i < 4; i++)
#pragma unroll
        for (int j = 0; j < 4; j++)
#pragma unroll
            for (int q = 0; q < 4; q++) acc[i][j][q] = 0.f;

    gemm_mainloop(A, Bw, As, Bs, tm, tn, acc);

    const int cbase = tn * 128 + wc * 64;          // multiple of 64, head-aligned
    const int sec = cbase >> 10;                   // 0=q 1=k 2=v
    const int h = (cbase & 1023) >> 6;
    float bias_c[4];
#pragma unroll
    for (int j = 0; j < 4; j++) bias_c[j] = bias[cbase + j * 16 + lr];

#pragma unroll
    for (int i = 0; i < 4; i++) {
#pragma unroll
        for (int r = 0; r < 4; r++) {
            const int m = tm * 128 + wr * 64 + i * 16 + (lane >> 4) * 4 + r;
            const int b = m >> 10, n = m & 1023;
            float vals[4];
#pragma unroll
            for (int j = 0; j < 4; j++) vals[j] = acc[i][j][r] + bias_c[j];
            if (sec == 2) {
#pragma unroll
                for (int j = 0; j < 4; j++) {
                    const int d = j * 16 + lr;
                    Vt[((size_t)((b * 16 + h) * 64 + d)) * 1024 + n] = f2bf(vals[j]);
                }
            } else {
#pragma unroll
                for (int j = 0; j < 4; j++) {
                    const int d = j * 16 + lr;
                    const float c = cosT[n * 64 + d];
                    const float s = sinT[n * 64 + d];
                    const float pr = vals[j ^ 2];          // paired element d ^ 32
                    float outv = vals[j] * c + (d < 32 ? -pr : pr) * s;
                    if (sec == 0) outv *= 0.125f;          // fold attn scale into Q
                    unsigned short* dst = (sec == 0) ? Qb : Kb;
                    dst[((size_t)((b * 16 + h) * 1024 + n)) * 64 + d] = f2bf(outv);
                }
            }
        }
    }
}

// ---------------- flash attention, swapped-operand structure ----------------
// grid (8 q-tiles, 64 bh); 4 waves/block, wave handles 32 q rows.
// QK^T computed as mfma(K, Q) -> S^T: lane holds one q-row (q = lane&15),
// k = kf*16 + (lane>>4)*4 + r  -> softmax is 2 shuffles per 16 q-rows.
// O accumulated transposed: mfma(V, P) -> O^T: col = q (lane-local rescale).
__global__ __launch_bounds__(256) void attn_kernel(
        const unsigned short* __restrict__ Qb, const unsigned short* __restrict__ Kb,
        const unsigned short* __restrict__ Vt, unsigned short* __restrict__ AO) {
    __shared__ __align__(16) unsigned short Pbuf[4][32 * 64];
    const int tid = threadIdx.x, lane = tid & 63, wv = tid >> 6;
    const int bh = blockIdx.y, qt = blockIdx.x;
    const int qbase = qt * 128 + wv * 32;
    const unsigned short* Qp = Qb + (size_t)bh * 65536;
    const unsigned short* Kp = Kb + (size_t)bh * 65536;
    const unsigned short* Vp = Vt + (size_t)bh * 65536;
    const int lr = lane & 15, lg = lane >> 4;

    // Q fragments (B-operand of swapped QK): qfr[qf][kc]
    bf16x8 qfr[2][2];
#pragma unroll
    for (int qf = 0; qf < 2; qf++)
#pragma unroll
        for (int kc = 0; kc < 2; kc++)
            qfr[qf][kc] = *reinterpret_cast<const bf16x8*>(Qp + (qbase + qf * 16 + lr) * 64 + kc * 32 + lg * 8);

    f32x4 o[4][2];                 // O^T: o[df][qf], row=d-local, col=q
    float m_[2], l_[2];
#pragma unroll
    for (int df = 0; df < 4; df++)
#pragma unroll
        for (int qf = 0; qf < 2; qf++)
#pragma unroll
            for (int r = 0; r < 4; r++) o[df][qf][r] = 0.f;
    m_[0] = m_[1] = -1e30f;
    l_[0] = l_[1] = 0.f;

    char* Pw = (char*)&Pbuf[wv][0];

    for (int kt = 0; kt < 1024; kt += 64) {
        f32x4 s[4][2];             // S^T: s[kf][qf]
#pragma unroll
        for (int kf = 0; kf < 4; kf++)
#pragma unroll
            for (int qf = 0; qf < 2; qf++)
#pragma unroll
                for (int r = 0; r < 4; r++) s[kf][qf][r] = 0.f;

        __builtin_amdgcn_s_setprio(1);
#pragma unroll
        for (int kc = 0; kc < 2; kc++) {
#pragma unroll
            for (int kf = 0; kf < 4; kf++) {
                const bf16x8 kfr = *reinterpret_cast<const bf16x8*>(Kp + (kt + kf * 16 + lr) * 64 + kc * 32 + lg * 8);
                s[kf][0] = __builtin_amdgcn_mfma_f32_16x16x32_bf16(kfr, qfr[0][kc], s[kf][0], 0, 0, 0);
                s[kf][1] = __builtin_amdgcn_mfma_f32_16x16x32_bf16(kfr, qfr[1][kc], s[kf][1], 0, 0, 0);
            }
        }
        __builtin_amdgcn_s_setprio(0);

        // online softmax: q = qf*16 + lr is lane-local
        float fsc[2];
#pragma unroll
        for (int qf = 0; qf < 2; qf++) {
            float mx = s[0][qf][0];
#pragma unroll
            for (int kf = 0; kf < 4; kf++)
#pragma unroll
                for (int r = 0; r < 4; r++) mx = fmaxf(mx, s[kf][qf][r]);
            mx = fmaxf(mx, __shfl_xor(mx, 16, 64));
            mx = fmaxf(mx, __shfl_xor(mx, 32, 64));
            const float mnew = fmaxf(m_[qf], mx);
            fsc[qf] = exp2f((m_[qf] - mnew) * LOG2E);
            m_[qf] = mnew;
            float rs = 0.f;
#pragma unroll
            for (int kf = 0; kf < 4; kf++)
#pragma unroll
                for (int r = 0; r < 4; r++) {
                    const float p = exp2f((s[kf][qf][r] - mnew) * LOG2E);
                    s[kf][qf][r] = p;
                    rs += p;
                }
            rs += __shfl_xor(rs, 16, 64);
            rs += __shfl_xor(rs, 32, 64);
            l_[qf] = l_[qf] * fsc[qf] + rs;
#pragma unroll
            for (int df = 0; df < 4; df++)
#pragma unroll
                for (int r = 0; r < 4; r++) o[df][qf][r] *= fsc[qf];
        }

        // P[q][k] -> LDS (row-major [32][64] bf16, XOR-swizzled), 8x ds_write_b64
#pragma unroll
        for (int qf = 0; qf < 2; qf++) {
            const int q = qf * 16 + lr;
#pragma unroll
            for (int kf = 0; kf < 4; kf++) {
                us4 pk;
                pk.x = f2bf(s[kf][qf][0]); pk.y = f2bf(s[kf][qf][1]);
                pk.z = f2bf(s[kf][qf][2]); pk.w = f2bf(s[kf][qf][3]);
                const int boff = (q * 128 + (kf * 16 + lg * 4) * 2) ^ ((q & 7) << 4);
                *reinterpret_cast<us4*>(Pw + boff) = pk;
            }
        }
        asm volatile("s_waitcnt lgkmcnt(0)" ::: "memory");

        // PV: O^T += mfma(V-frag [d][k], P-frag [q][k])
#pragma unroll
        for (int kc = 0; kc < 2; kc++) {
            bf16x8 pfr[2];
#pragma unroll
            for (int qf = 0; qf < 2; qf++) {
                const int q = qf * 16 + lr;
                const int boff = (q * 128 + (kc * 32 + lg * 8) * 2) ^ ((q & 7) << 4);
                pfr[qf] = *reinterpret_cast<const bf16x8*>(Pw + boff);
            }
            __builtin_amdgcn_s_setprio(1);
#pragma unroll
            for (int df = 0; df < 4; df++) {
                const bf16x8 vfr = *reinterpret_cast<const bf16x8*>(Vp + (df * 16 + lr) * 1024 + kt + kc * 32 + lg * 8);
                o[df][0] = __builtin_amdgcn_mfma_f32_16x16x32_bf16(vfr, pfr[0], o[df][0], 0, 0, 0);
                o[df][1] = __builtin_amdgcn_mfma_f32_16x16x32_bf16(vfr, pfr[1], o[df][1], 0, 0, 0);
            }
            __builtin_amdgcn_s_setprio(0);
        }
    }

    // epilogue: O^T -> AO [b][n=q][h*64+d] bf16; d = df*16 + lg*4 + r (consecutive r)
    const int b = bh >> 4, h = bh & 15;
    const float rinv0 = 1.f / l_[0], rinv1 = 1.f / l_[1];
#pragma unroll
    for (int qf = 0; qf < 2; qf++) {
        const int q = qbase + qf * 16 + lr;
        const float rinv = qf ? rinv1 : rinv0;
#pragma unroll
        for (int df = 0; df < 4; df++) {
            us4 pk;
            pk.x = f2bf(o[df][qf][0] * rinv); pk.y = f2bf(o[df][qf][1] * rinv);
            pk.z = f2bf(o[df][qf][2] * rinv); pk.w = f2bf(o[df][qf][3] * rinv);
            *reinterpret_cast<us4*>(AO + (size_t)(b * 1024 + q) * 1024 + h * 64 + df * 16 + lg * 4) = pk;
        }
    }
}

// ---------------- GEMM2: out = AO @ proj_w^T + proj_b (fp32 out) ----------------
__global__ __launch_bounds__(256) void gemm_proj_kernel(
        const unsigned short* __restrict__ A, const unsigned short* __restrict__ Bw,
        const float* __restrict__ bias, float* __restrict__ out) {
    __shared__ __align__(16) unsigned short As[128 * 32];
    __shared__ __align__(16) unsigned short Bs[128 * 32];
    const int tid = threadIdx.x;
    const int lane = tid & 63;
    const int wv = tid >> 6;
    const int wr = wv >> 1, wc = wv & 1;
    const int tm = blockIdx.y, tn = blockIdx.x;
    const int lr = lane & 15;

    f32x4 acc[4][4];
#pragma unroll
    for (int i = 0; i < 4; i++)
#pragma unroll
        for (int j = 0; j < 4; j++)
#pragma unroll
            for (int q = 0; q < 4; q++) acc[i][j][q] = 0.f;

    gemm_mainloop(A, Bw, As, Bs, tm, tn, acc);

#pragma unroll
    for (int i = 0; i < 4; i++)
#pragma unroll
        for (int j = 0; j < 4; j++)
#pragma unroll
            for (int r = 0; r < 4; r++) {
                const int row = tm * 128 + wr * 64 + i * 16 + (lane >> 4) * 4 + r;
                const int col = tn * 128 + wc * 64 + j * 16 + lr;
                out[(size_t)row * 1024 + col] = acc[i][j][r] + bias[col];
            }
}

extern "C" void kernel_launch(void* const* d_in, const int* in_sizes, int n_in,
                              void* d_out, int out_size, void* d_ws, size_t ws_size,
                              hipStream_t stream) {
    const float* x      = (const float*)d_in[0];
    const float* cosT   = (const float*)d_in[1];
    const float* sinT   = (const float*)d_in[2];
    const float* qkv_w  = (const float*)d_in[3];
    const float* qkv_b  = (const float*)d_in[4];
    const float* proj_w = (const float*)d_in[5];
    const float* proj_b = (const float*)d_in[6];
    float* out = (float*)d_out;

    char* ws = (char*)d_ws;
    unsigned short* xb    = (unsigned short*)(ws);                 // 8 MB  [4096][1024]
    unsigned short* wqkv  = (unsigned short*)(ws + (8u << 20));    // 6 MB  [3072][1024]
    unsigned short* wproj = (unsigned short*)(ws + (14u << 20));   // 2 MB  [1024][1024]
    unsigned short* Qb    = (unsigned short*)(ws + (16u << 20));   // 8 MB  [64][1024][64]
    unsigned short* Kb    = (unsigned short*)(ws + (24u << 20));   // 8 MB  [64][1024][64]
    unsigned short* Vt    = (unsigned short*)(ws + (32u << 20));   // 8 MB  [64][64][1024]
    unsigned short* AO    = (unsigned short*)(ws + (40u << 20));   // 8 MB  [4096][1024]

    cvt_kernel<<<2048, 256, 0, stream>>>(x, xb, 4096 * 1024);
    cvt_kernel<<<2048, 256, 0, stream>>>(qkv_w, wqkv, 3072 * 1024);
    cvt_kernel<<<1024, 256, 0, stream>>>(proj_w, wproj, 1024 * 1024);
    gemm_qkv_kernel<<<dim3(24, 32), 256, 0, stream>>>(xb, wqkv, qkv_b, cosT, sinT, Qb, Kb, Vt);
    attn_kernel<<<dim3(8, 64), 256, 0, stream>>>(Qb, Kb, Vt, AO);
    gemm_proj_kernel<<<dim3(8, 32), 256, 0, stream>>>(AO, wproj, proj_b, out);
}

// Round 3
// 145.211 us; speedup vs baseline: 1.3289x; 1.1015x over previous
//
#include <hip/hip_runtime.h>

typedef __attribute__((ext_vector_type(8))) short bf16x8;
typedef __attribute__((ext_vector_type(4))) float f32x4;
typedef __attribute__((ext_vector_type(4))) unsigned short us4;

#define LOG2E 1.44269504088896f

__device__ inline unsigned short f2bf(float f) {
    unsigned u = __float_as_uint(f);
    u += 0x7fffu + ((u >> 16) & 1u);
    return (unsigned short)(u >> 16);
}

__device__ inline unsigned cvt_pk_bf16(float lo, float hi) {
    unsigned r;
    asm("v_cvt_pk_bf16_f32 %0, %1, %2" : "=v"(r) : "v"(lo), "v"(hi));
    return r;
}

// ---------------- fp32 -> bf16 convert (n % 4 == 0) ----------------
__global__ void cvt_kernel(const float* __restrict__ src, unsigned short* __restrict__ dst, int n) {
    int i = (blockIdx.x * blockDim.x + threadIdx.x) * 4;
    const int stride = gridDim.x * blockDim.x * 4;
    for (; i < n; i += stride) {
        const float4 v = *reinterpret_cast<const float4*>(src + i);
        us4 o;
        o.x = f2bf(v.x); o.y = f2bf(v.y); o.z = f2bf(v.z); o.w = f2bf(v.w);
        *reinterpret_cast<us4*>(dst + i) = o;
    }
}

// ---------------- shared GEMM mainloop ----------------
// A [M][1024] bf16 row-major, Bw [Ncols][1024] bf16 row-major (computes A.Bw^T).
// 128x128 tile, 4 waves in 2x2, each wave 64x64 (4x4 fragments of 16x16x32 MFMA).
__device__ inline void gemm_mainloop(const unsigned short* __restrict__ A,
                                     const unsigned short* __restrict__ Bw,
                                     unsigned short* As, unsigned short* Bs,
                                     int tm, int tn, f32x4 (&acc)[4][4]) {
    const int K = 1024;
    const int tid = threadIdx.x;
    const int lane = tid & 63;
    const int wv = tid >> 6;
    const int wr = wv >> 1, wc = wv & 1;
    const int lr = lane & 15, lk = (lane >> 4) * 8;

    const unsigned short* Ag = A + (size_t)(tm * 128 + (tid >> 2)) * K + (tid & 3) * 8;
    const unsigned short* Bg = Bw + (size_t)(tn * 128 + (tid >> 2)) * K + (tid & 3) * 8;
    unsigned short* AsD = As + tid * 8;
    unsigned short* BsD = Bs + tid * 8;

    for (int k0 = 0; k0 < K; k0 += 32) {
        __builtin_amdgcn_global_load_lds((const __attribute__((address_space(1))) void*)(Ag + k0),
                                         (__attribute__((address_space(3))) void*)AsD, 16, 0, 0);
        __builtin_amdgcn_global_load_lds((const __attribute__((address_space(1))) void*)(Ag + 64 * K + k0),
                                         (__attribute__((address_space(3))) void*)(AsD + 2048), 16, 0, 0);
        __builtin_amdgcn_global_load_lds((const __attribute__((address_space(1))) void*)(Bg + k0),
                                         (__attribute__((address_space(3))) void*)BsD, 16, 0, 0);
        __builtin_amdgcn_global_load_lds((const __attribute__((address_space(1))) void*)(Bg + 64 * K + k0),
                                         (__attribute__((address_space(3))) void*)(BsD + 2048), 16, 0, 0);
        __syncthreads();
        bf16x8 af[4], bfv[4];
#pragma unroll
        for (int i = 0; i < 4; i++) {
            af[i]  = *reinterpret_cast<const bf16x8*>(As + (wr * 64 + i * 16 + lr) * 32 + lk);
            bfv[i] = *reinterpret_cast<const bf16x8*>(Bs + (wc * 64 + i * 16 + lr) * 32 + lk);
        }
#pragma unroll
        for (int i = 0; i < 4; i++)
#pragma unroll
            for (int j = 0; j < 4; j++)
                acc[i][j] = __builtin_amdgcn_mfma_f32_16x16x32_bf16(af[i], bfv[j], acc[i][j], 0, 0, 0);
        __syncthreads();
    }
}

// ---------------- GEMM1: qkv = x @ qkv_w^T + b, RoPE on q,k, scatter ----------------
__global__ __launch_bounds__(256) void gemm_qkv_kernel(
        const unsigned short* __restrict__ A, const unsigned short* __restrict__ Bw,
        const float* __restrict__ bias, const float* __restrict__ cosT, const float* __restrict__ sinT,
        unsigned short* __restrict__ Qb, unsigned short* __restrict__ Kb, unsigned short* __restrict__ Vt) {
    __shared__ __align__(16) unsigned short As[128 * 32];
    __shared__ __align__(16) unsigned short Bs[128 * 32];
    const int tid = threadIdx.x;
    const int lane = tid & 63;
    const int wv = tid >> 6;
    const int wr = wv >> 1, wc = wv & 1;
    const int tm = blockIdx.y, tn = blockIdx.x;
    const int lr = lane & 15;

    f32x4 acc[4][4];
#pragma unroll
    for (int i = 0; i < 4; i++)
#pragma unroll
        for (int j = 0; j < 4; j++)
#pragma unroll
            for (int q = 0; q < 4; q++) acc[i][j][q] = 0.f;

    gemm_mainloop(A, Bw, As, Bs, tm, tn, acc);

    const int cbase = tn * 128 + wc * 64;          // multiple of 64, head-aligned
    const int sec = cbase >> 10;                   // 0=q 1=k 2=v
    const int h = (cbase & 1023) >> 6;
    float bias_c[4];
#pragma unroll
    for (int j = 0; j < 4; j++) bias_c[j] = bias[cbase + j * 16 + lr];

#pragma unroll
    for (int i = 0; i < 4; i++) {
#pragma unroll
        for (int r = 0; r < 4; r++) {
            const int m = tm * 128 + wr * 64 + i * 16 + (lane >> 4) * 4 + r;
            const int b = m >> 10, n = m & 1023;
            float vals[4];
#pragma unroll
            for (int j = 0; j < 4; j++) vals[j] = acc[i][j][r] + bias_c[j];
            if (sec == 2) {
#pragma unroll
                for (int j = 0; j < 4; j++) {
                    const int d = j * 16 + lr;
                    Vt[((size_t)((b * 16 + h) * 64 + d)) * 1024 + n] = f2bf(vals[j]);
                }
            } else {
#pragma unroll
                for (int j = 0; j < 4; j++) {
                    const int d = j * 16 + lr;
                    const float c = cosT[n * 64 + d];
                    const float s = sinT[n * 64 + d];
                    const float pr = vals[j ^ 2];          // paired element d ^ 32
                    float outv = vals[j] * c + (d < 32 ? -pr : pr) * s;
                    if (sec == 0) outv *= 0.125f;          // fold attn scale into Q
                    unsigned short* dst = (sec == 0) ? Qb : Kb;
                    dst[((size_t)((b * 16 + h) * 1024 + n)) * 64 + d] = f2bf(outv);
                }
            }
        }
    }
}

// ---------------- flash attention, swapped + pi-permuted, register-only P ----------------
// grid (64 bh = x for XCD pinning, 8 qt = y); 4 waves/block, wave owns 32 q rows.
// QK^T as mfma(K,Q) with K rows loaded at pi-permuted addresses so the S
// registers are already in PV B-fragment order: P never touches LDS.
// pi(kf*16+i) = (kf>>1)*32 + (i>>2)*8 + (kf&1)*4 + (i&3).
__global__ __launch_bounds__(256, 2) void attn_kernel(
        const unsigned short* __restrict__ Qb, const unsigned short* __restrict__ Kb,
        const unsigned short* __restrict__ Vt, unsigned short* __restrict__ AO) {
    const int tid = threadIdx.x, lane = tid & 63, wv = tid >> 6;
    const int bh = blockIdx.x, qt = blockIdx.y;
    const int qbase = qt * 128 + wv * 32;
    const unsigned short* Qp = Qb + (size_t)bh * 65536;
    const unsigned short* Kp = Kb + (size_t)bh * 65536;
    const unsigned short* Vp = Vt + (size_t)bh * 65536;
    const int lr = lane & 15, lg = lane >> 4;
    const int koff = (lr >> 2) * 8 + (lr & 3);     // lane part of pi

    bf16x8 qfr[2][2];
#pragma unroll
    for (int qf = 0; qf < 2; qf++)
#pragma unroll
        for (int kc = 0; kc < 2; kc++)
            qfr[qf][kc] = *reinterpret_cast<const bf16x8*>(Qp + (qbase + qf * 16 + lr) * 64 + kc * 32 + lg * 8);

    f32x4 o[4][2];                 // O^T: o[df][qf]
    float m_[2], l_[2];            // l_ is a per-lane PARTIAL sum (reduced at end)
#pragma unroll
    for (int df = 0; df < 4; df++)
#pragma unroll
        for (int qf = 0; qf < 2; qf++)
#pragma unroll
            for (int r = 0; r < 4; r++) o[df][qf][r] = 0.f;
    m_[0] = m_[1] = -1e30f;
    l_[0] = l_[1] = 0.f;

    auto QK = [&](f32x4 (&s)[4][2], int kt) {
#pragma unroll
        for (int kf = 0; kf < 4; kf++)
#pragma unroll
            for (int qf = 0; qf < 2; qf++)
#pragma unroll
                for (int r = 0; r < 4; r++) s[kf][qf][r] = 0.f;
        __builtin_amdgcn_s_setprio(1);
#pragma unroll
        for (int kc = 0; kc < 2; kc++) {
#pragma unroll
            for (int kf = 0; kf < 4; kf++) {
                const int row = kt + ((kf >> 1) << 5) + ((kf & 1) << 2) + koff;   // pi-permuted
                const bf16x8 kfr = *reinterpret_cast<const bf16x8*>(Kp + row * 64 + kc * 32 + lg * 8);
                s[kf][0] = __builtin_amdgcn_mfma_f32_16x16x32_bf16(kfr, qfr[0][kc], s[kf][0], 0, 0, 0);
                s[kf][1] = __builtin_amdgcn_mfma_f32_16x16x32_bf16(kfr, qfr[1][kc], s[kf][1], 0, 0, 0);
            }
        }
        __builtin_amdgcn_s_setprio(0);
    };

    auto SMPV = [&](f32x4 (&s)[4][2], int kt) {
        // online softmax with defer-max; q = qf*16 + lr lane-local
#pragma unroll
        for (int qf = 0; qf < 2; qf++) {
            float mx = s[0][qf][0];
#pragma unroll
            for (int kf = 0; kf < 4; kf++)
#pragma unroll
                for (int r = 0; r < 4; r++) mx = fmaxf(mx, s[kf][qf][r]);
            if (!__all(mx <= m_[qf] + 8.f)) {
                mx = fmaxf(mx, __shfl_xor(mx, 16, 64));
                mx = fmaxf(mx, __shfl_xor(mx, 32, 64));
                const float mnew = fmaxf(m_[qf], mx);
                const float fsc = exp2f((m_[qf] - mnew) * LOG2E);
                m_[qf] = mnew;
                l_[qf] *= fsc;
#pragma unroll
                for (int df = 0; df < 4; df++)
#pragma unroll
                    for (int r = 0; r < 4; r++) o[df][qf][r] *= fsc;
            }
            float rs = 0.f;
#pragma unroll
            for (int kf = 0; kf < 4; kf++)
#pragma unroll
                for (int r = 0; r < 4; r++) {
                    const float p = exp2f((s[kf][qf][r] - m_[qf]) * LOG2E);
                    s[kf][qf][r] = p;
                    rs += p;
                }
            l_[qf] += rs;
        }
        // PV: O^T += mfma(V-frag, P-frag); P packed straight from registers
#pragma unroll
        for (int kc = 0; kc < 2; kc++) {
            bf16x8 pfr[2];
#pragma unroll
            for (int qf = 0; qf < 2; qf++) {
                union { bf16x8 v; unsigned u[4]; } pk;
                pk.u[0] = cvt_pk_bf16(s[2 * kc][qf][0], s[2 * kc][qf][1]);
                pk.u[1] = cvt_pk_bf16(s[2 * kc][qf][2], s[2 * kc][qf][3]);
                pk.u[2] = cvt_pk_bf16(s[2 * kc + 1][qf][0], s[2 * kc + 1][qf][1]);
                pk.u[3] = cvt_pk_bf16(s[2 * kc + 1][qf][2], s[2 * kc + 1][qf][3]);
                pfr[qf] = pk.v;
            }
            __builtin_amdgcn_s_setprio(1);
#pragma unroll
            for (int df = 0; df < 4; df++) {
                const bf16x8 vfr = *reinterpret_cast<const bf16x8*>(Vp + (df * 16 + lr) * 1024 + kt + kc * 32 + lg * 8);
                o[df][0] = __builtin_amdgcn_mfma_f32_16x16x32_bf16(vfr, pfr[0], o[df][0], 0, 0, 0);
                o[df][1] = __builtin_amdgcn_mfma_f32_16x16x32_bf16(vfr, pfr[1], o[df][1], 0, 0, 0);
            }
            __builtin_amdgcn_s_setprio(0);
        }
    };

    // 2-tile software pipeline: QK(t+1) overlaps softmax+PV(t)
    f32x4 sA[4][2], sB[4][2];
    QK(sA, 0);
    for (int kt = 0; kt < 1024; kt += 128) {
        QK(sB, kt + 64);
        SMPV(sA, kt);
        if (kt + 128 < 1024) QK(sA, kt + 128);
        SMPV(sB, kt + 64);
    }

    // epilogue: reduce partial l across the 4 lanes per q-row, write O^T -> AO
    const int b = bh >> 4, h = bh & 15;
#pragma unroll
    for (int qf = 0; qf < 2; qf++) {
        float lt = l_[qf];
        lt += __shfl_xor(lt, 16, 64);
        lt += __shfl_xor(lt, 32, 64);
        const float rinv = 1.f / lt;
        const int q = qbase + qf * 16 + lr;
#pragma unroll
        for (int df = 0; df < 4; df++) {
            us4 pk;
            pk.x = f2bf(o[df][qf][0] * rinv); pk.y = f2bf(o[df][qf][1] * rinv);
            pk.z = f2bf(o[df][qf][2] * rinv); pk.w = f2bf(o[df][qf][3] * rinv);
            *reinterpret_cast<us4*>(AO + (size_t)(b * 1024 + q) * 1024 + h * 64 + df * 16 + lg * 4) = pk;
        }
    }
}

// ---------------- GEMM2: out = AO @ proj_w^T + proj_b (fp32 out) ----------------
__global__ __launch_bounds__(256) void gemm_proj_kernel(
        const unsigned short* __restrict__ A, const unsigned short* __restrict__ Bw,
        const float* __restrict__ bias, float* __restrict__ out) {
    __shared__ __align__(16) unsigned short As[128 * 32];
    __shared__ __align__(16) unsigned short Bs[128 * 32];
    const int tid = threadIdx.x;
    const int lane = tid & 63;
    const int wv = tid >> 6;
    const int wr = wv >> 1, wc = wv & 1;
    const int tm = blockIdx.y, tn = blockIdx.x;
    const int lr = lane & 15;

    f32x4 acc[4][4];
#pragma unroll
    for (int i = 0; i < 4; i++)
#pragma unroll
        for (int j = 0; j < 4; j++)
#pragma unroll
            for (int q = 0; q < 4; q++) acc[i][j][q] = 0.f;

    gemm_mainloop(A, Bw, As, Bs, tm, tn, acc);

#pragma unroll
    for (int i = 0; i < 4; i++)
#pragma unroll
        for (int j = 0; j < 4; j++)
#pragma unroll
            for (int r = 0; r < 4; r++) {
                const int row = tm * 128 + wr * 64 + i * 16 + (lane >> 4) * 4 + r;
                const int col = tn * 128 + wc * 64 + j * 16 + lr;
                out[(size_t)row * 1024 + col] = acc[i][j][r] + bias[col];
            }
}

extern "C" void kernel_launch(void* const* d_in, const int* in_sizes, int n_in,
                              void* d_out, int out_size, void* d_ws, size_t ws_size,
                              hipStream_t stream) {
    const float* x      = (const float*)d_in[0];
    const float* cosT   = (const float*)d_in[1];
    const float* sinT   = (const float*)d_in[2];
    const float* qkv_w  = (const float*)d_in[3];
    const float* qkv_b  = (const float*)d_in[4];
    const float* proj_w = (const float*)d_in[5];
    const float* proj_b = (const float*)d_in[6];
    float* out = (float*)d_out;

    char* ws = (char*)d_ws;
    unsigned short* xb    = (unsigned short*)(ws);                 // 8 MB  [4096][1024]
    unsigned short* wqkv  = (unsigned short*)(ws + (8u << 20));    // 6 MB  [3072][1024]
    unsigned short* wproj = (unsigned short*)(ws + (14u << 20));   // 2 MB  [1024][1024]
    unsigned short* Qb    = (unsigned short*)(ws + (16u << 20));   // 8 MB  [64][1024][64]
    unsigned short* Kb    = (unsigned short*)(ws + (24u << 20));   // 8 MB  [64][1024][64]
    unsigned short* Vt    = (unsigned short*)(ws + (32u << 20));   // 8 MB  [64][64][1024]
    unsigned short* AO    = (unsigned short*)(ws + (40u << 20));   // 8 MB  [4096][1024]

    cvt_kernel<<<2048, 256, 0, stream>>>(x, xb, 4096 * 1024);
    cvt_kernel<<<2048, 256, 0, stream>>>(qkv_w, wqkv, 3072 * 1024);
    cvt_kernel<<<1024, 256, 0, stream>>>(proj_w, wproj, 1024 * 1024);
    gemm_qkv_kernel<<<dim3(24, 32), 256, 0, stream>>>(xb, wqkv, qkv_b, cosT, sinT, Qb, Kb, Vt);
    attn_kernel<<<dim3(64, 8), 256, 0, stream>>>(Qb, Kb, Vt, AO);
    gemm_proj_kernel<<<dim3(8, 32), 256, 0, stream>>>(AO, wproj, proj_b, out);
}

// Round 4
// 116.716 us; speedup vs baseline: 1.6533x; 1.2441x over previous
//
#include <hip/hip_runtime.h>

typedef __attribute__((ext_vector_type(8))) short bf16x8;
typedef __attribute__((ext_vector_type(4))) float f32x4;
typedef __attribute__((ext_vector_type(4))) unsigned short us4;

#define LOG2E 1.44269504088896f

__device__ inline unsigned short f2bf(float f) {
    unsigned u = __float_as_uint(f);
    u += 0x7fffu + ((u >> 16) & 1u);
    return (unsigned short)(u >> 16);
}

__device__ inline unsigned cvt_pk_bf16(float lo, float hi) {
    unsigned r;
    asm("v_cvt_pk_bf16_f32 %0, %1, %2" : "=v"(r) : "v"(lo), "v"(hi));
    return r;
}

// ---------------- fp32 -> bf16 convert (n % 4 == 0) ----------------
__global__ void cvt_kernel(const float* __restrict__ src, unsigned short* __restrict__ dst, int n) {
    int i = (blockIdx.x * blockDim.x + threadIdx.x) * 4;
    const int stride = gridDim.x * blockDim.x * 4;
    for (; i < n; i += stride) {
        const float4 v = *reinterpret_cast<const float4*>(src + i);
        us4 o;
        o.x = f2bf(v.x); o.y = f2bf(v.y); o.z = f2bf(v.z); o.w = f2bf(v.w);
        *reinterpret_cast<us4*>(dst + i) = o;
    }
}

// ---------------- shared GEMM mainloop ----------------
__device__ inline void gemm_mainloop(const unsigned short* __restrict__ A,
                                     const unsigned short* __restrict__ Bw,
                                     unsigned short* As, unsigned short* Bs,
                                     int tm, int tn, f32x4 (&acc)[4][4]) {
    const int K = 1024;
    const int tid = threadIdx.x;
    const int lane = tid & 63;
    const int wv = tid >> 6;
    const int wr = wv >> 1, wc = wv & 1;
    const int lr = lane & 15, lk = (lane >> 4) * 8;

    const unsigned short* Ag = A + (size_t)(tm * 128 + (tid >> 2)) * K + (tid & 3) * 8;
    const unsigned short* Bg = Bw + (size_t)(tn * 128 + (tid >> 2)) * K + (tid & 3) * 8;
    unsigned short* AsD = As + tid * 8;
    unsigned short* BsD = Bs + tid * 8;

    for (int k0 = 0; k0 < K; k0 += 32) {
        __builtin_amdgcn_global_load_lds((const __attribute__((address_space(1))) void*)(Ag + k0),
                                         (__attribute__((address_space(3))) void*)AsD, 16, 0, 0);
        __builtin_amdgcn_global_load_lds((const __attribute__((address_space(1))) void*)(Ag + 64 * K + k0),
                                         (__attribute__((address_space(3))) void*)(AsD + 2048), 16, 0, 0);
        __builtin_amdgcn_global_load_lds((const __attribute__((address_space(1))) void*)(Bg + k0),
                                         (__attribute__((address_space(3))) void*)BsD, 16, 0, 0);
        __builtin_amdgcn_global_load_lds((const __attribute__((address_space(1))) void*)(Bg + 64 * K + k0),
                                         (__attribute__((address_space(3))) void*)(BsD + 2048), 16, 0, 0);
        __syncthreads();
        bf16x8 af[4], bfv[4];
#pragma unroll
        for (int i = 0; i < 4; i++) {
            af[i]  = *reinterpret_cast<const bf16x8*>(As + (wr * 64 + i * 16 + lr) * 32 + lk);
            bfv[i] = *reinterpret_cast<const bf16x8*>(Bs + (wc * 64 + i * 16 + lr) * 32 + lk);
        }
#pragma unroll
        for (int i = 0; i < 4; i++)
#pragma unroll
            for (int j = 0; j < 4; j++)
                acc[i][j] = __builtin_amdgcn_mfma_f32_16x16x32_bf16(af[i], bfv[j], acc[i][j], 0, 0, 0);
        __syncthreads();
    }
}

// ---------------- GEMM1: qkv = x @ qkv_w^T + b, RoPE on q,k, scatter ----------------
// Q is pre-scaled by 0.125 * LOG2E so attention softmax can use exp2 natively.
__global__ __launch_bounds__(256) void gemm_qkv_kernel(
        const unsigned short* __restrict__ A, const unsigned short* __restrict__ Bw,
        const float* __restrict__ bias, const float* __restrict__ cosT, const float* __restrict__ sinT,
        unsigned short* __restrict__ Qb, unsigned short* __restrict__ Kb, unsigned short* __restrict__ Vt) {
    __shared__ __align__(16) unsigned short As[128 * 32];
    __shared__ __align__(16) unsigned short Bs[128 * 32];
    const int tid = threadIdx.x;
    const int lane = tid & 63;
    const int wv = tid >> 6;
    const int wr = wv >> 1, wc = wv & 1;
    const int tm = blockIdx.y, tn = blockIdx.x;
    const int lr = lane & 15;

    f32x4 acc[4][4];
#pragma unroll
    for (int i = 0; i < 4; i++)
#pragma unroll
        for (int j = 0; j < 4; j++)
#pragma unroll
            for (int q = 0; q < 4; q++) acc[i][j][q] = 0.f;

    gemm_mainloop(A, Bw, As, Bs, tm, tn, acc);

    const int cbase = tn * 128 + wc * 64;          // multiple of 64, head-aligned
    const int sec = cbase >> 10;                   // 0=q 1=k 2=v
    const int h = (cbase & 1023) >> 6;
    float bias_c[4];
#pragma unroll
    for (int j = 0; j < 4; j++) bias_c[j] = bias[cbase + j * 16 + lr];

#pragma unroll
    for (int i = 0; i < 4; i++) {
#pragma unroll
        for (int r = 0; r < 4; r++) {
            const int m = tm * 128 + wr * 64 + i * 16 + (lane >> 4) * 4 + r;
            const int b = m >> 10, n = m & 1023;
            float vals[4];
#pragma unroll
            for (int j = 0; j < 4; j++) vals[j] = acc[i][j][r] + bias_c[j];
            if (sec == 2) {
#pragma unroll
                for (int j = 0; j < 4; j++) {
                    const int d = j * 16 + lr;
                    Vt[((size_t)((b * 16 + h) * 64 + d)) * 1024 + n] = f2bf(vals[j]);
                }
            } else {
#pragma unroll
                for (int j = 0; j < 4; j++) {
                    const int d = j * 16 + lr;
                    const float c = cosT[n * 64 + d];
                    const float s = sinT[n * 64 + d];
                    const float pr = vals[j ^ 2];          // paired element d ^ 32
                    float outv = vals[j] * c + (d < 32 ? -pr : pr) * s;
                    if (sec == 0) outv *= 0.125f * LOG2E;  // fold scale + log2(e) into Q
                    unsigned short* dst = (sec == 0) ? Qb : Kb;
                    dst[((size_t)((b * 16 + h) * 1024 + n)) * 64 + d] = f2bf(outv);
                }
            }
        }
    }
}

// ---------------- flash attention: LDS-staged K/V, pi-permuted register-only P ----------
// grid (64 bh, 16 qt); 4 waves/block, each owns 16 q rows. K/V tiles (64 kv rows)
// double-buffered in LDS via global_load_lds; swizzled layout: LDS[row][c] holds
// global (row, c ^ swz(row)), swz(r) = (r&3)|((r>>1)&4); readers XOR the same.
// QK^T as mfma(K,Q) with pi-permuted K rows so S regs land in PV-B-fragment order.
__global__ __launch_bounds__(256, 4) void attn_kernel(
        const unsigned short* __restrict__ Qb, const unsigned short* __restrict__ Kb,
        const unsigned short* __restrict__ Vt, unsigned short* __restrict__ AO) {
    __shared__ __align__(16) unsigned short KVs[2][8192];   // [buf][K:4096 | V:4096] ushorts
    const int tid = threadIdx.x, lane = tid & 63, wv = tid >> 6;
    const int bh = blockIdx.x, qt = blockIdx.y;
    const int qbase = qt * 64 + wv * 16;
    const unsigned short* Qp = Qb + (size_t)bh * 65536;
    const unsigned short* Kp = Kb + (size_t)bh * 65536;
    const unsigned short* Vp = Vt + (size_t)bh * 65536;
    const int lr = lane & 15, lg = lane >> 4;
    const int koff = (lr >> 2) * 8 + (lr & 3);     // lane part of pi

    // staging: thread handles slots tid and tid+256 for both K and V
    const int s1 = tid, s2 = tid + 256;
    const int r1 = s1 >> 3, r2 = s2 >> 3;
    const int sc1 = (s1 & 7) ^ ((r1 & 3) | ((r1 >> 1) & 4));
    const int sc2 = (s2 & 7) ^ ((r2 & 3) | ((r2 >> 1) & 4));
    const unsigned short* Ks1 = Kp + r1 * 64 + sc1 * 8;
    const unsigned short* Ks2 = Kp + r2 * 64 + sc2 * 8;
    const unsigned short* Vs1 = Vp + r1 * 1024 + sc1 * 8;
    const unsigned short* Vs2 = Vp + r2 * 1024 + sc2 * 8;

    auto STAGE = [&](int buf, int kt) {
        unsigned short* base = &KVs[buf][0];
        __builtin_amdgcn_global_load_lds((const __attribute__((address_space(1))) void*)(Ks1 + kt * 64),
                                         (__attribute__((address_space(3))) void*)(base + s1 * 8), 16, 0, 0);
        __builtin_amdgcn_global_load_lds((const __attribute__((address_space(1))) void*)(Ks2 + kt * 64),
                                         (__attribute__((address_space(3))) void*)(base + s2 * 8), 16, 0, 0);
        __builtin_amdgcn_global_load_lds((const __attribute__((address_space(1))) void*)(Vs1 + kt),
                                         (__attribute__((address_space(3))) void*)(base + 4096 + s1 * 8), 16, 0, 0);
        __builtin_amdgcn_global_load_lds((const __attribute__((address_space(1))) void*)(Vs2 + kt),
                                         (__attribute__((address_space(3))) void*)(base + 4096 + s2 * 8), 16, 0, 0);
    };

    bf16x8 qfr[2];
#pragma unroll
    for (int kc = 0; kc < 2; kc++)
        qfr[kc] = *reinterpret_cast<const bf16x8*>(Qp + (qbase + lr) * 64 + kc * 32 + lg * 8);

    f32x4 o[4];
    float m_ = -1e30f, l_ = 0.f;
#pragma unroll
    for (int df = 0; df < 4; df++)
#pragma unroll
        for (int r = 0; r < 4; r++) o[df][r] = 0.f;

    STAGE(0, 0);
    for (int t = 0; t < 16; t++) {
        const int cur = t & 1;
        if (t < 15) {
            STAGE(cur ^ 1, (t + 1) * 64);
            asm volatile("s_waitcnt vmcnt(4)" ::: "memory");
        } else {
            asm volatile("s_waitcnt vmcnt(0)" ::: "memory");
        }
        __builtin_amdgcn_s_barrier();
        __builtin_amdgcn_sched_barrier(0);

        const unsigned short* Kl = &KVs[cur][0];
        const unsigned short* Vl = &KVs[cur][4096];

        // QK^T: s[kf] lane(lr,lg)[r] = score(q=lr, k = pi(kf, lg*4+r))
        f32x4 s[4];
#pragma unroll
        for (int kf = 0; kf < 4; kf++)
#pragma unroll
            for (int r = 0; r < 4; r++) s[kf][r] = 0.f;
        __builtin_amdgcn_s_setprio(1);
#pragma unroll
        for (int kc = 0; kc < 2; kc++) {
#pragma unroll
            for (int kf = 0; kf < 4; kf++) {
                const int row = ((kf >> 1) << 5) + ((kf & 1) << 2) + koff;
                const int col = (kc * 4 + lg) ^ ((row & 3) | ((row >> 1) & 4));
                const bf16x8 kfr = *reinterpret_cast<const bf16x8*>(Kl + row * 64 + col * 8);
                s[kf] = __builtin_amdgcn_mfma_f32_16x16x32_bf16(kfr, qfr[kc], s[kf], 0, 0, 0);
            }
        }
        __builtin_amdgcn_s_setprio(0);

        // online softmax (exp2 domain; scores pre-scaled by log2e); q = lr lane-local
        float mx = s[0][0];
#pragma unroll
        for (int kf = 0; kf < 4; kf++)
#pragma unroll
            for (int r = 0; r < 4; r++) mx = fmaxf(mx, s[kf][r]);
        if (!__all(mx <= m_ + 11.0f)) {
            mx = fmaxf(mx, __shfl_xor(mx, 16, 64));
            mx = fmaxf(mx, __shfl_xor(mx, 32, 64));
            const float mnew = fmaxf(m_, mx);
            const float fsc = exp2f(m_ - mnew);
            m_ = mnew;
            l_ *= fsc;
#pragma unroll
            for (int df = 0; df < 4; df++)
#pragma unroll
                for (int r = 0; r < 4; r++) o[df][r] *= fsc;
        }
        float rs = 0.f;
#pragma unroll
        for (int kf = 0; kf < 4; kf++)
#pragma unroll
            for (int r = 0; r < 4; r++) {
                const float p = exp2f(s[kf][r] - m_);
                s[kf][r] = p;
                rs += p;
            }
        l_ += rs;

        // PV: O^T += mfma(V-frag, P-frag); P packed straight from registers
#pragma unroll
        for (int kc = 0; kc < 2; kc++) {
            union { bf16x8 v; unsigned u[4]; } pk;
            pk.u[0] = cvt_pk_bf16(s[2 * kc][0], s[2 * kc][1]);
            pk.u[1] = cvt_pk_bf16(s[2 * kc][2], s[2 * kc][3]);
            pk.u[2] = cvt_pk_bf16(s[2 * kc + 1][0], s[2 * kc + 1][1]);
            pk.u[3] = cvt_pk_bf16(s[2 * kc + 1][2], s[2 * kc + 1][3]);
            const bf16x8 pfr = pk.v;
            __builtin_amdgcn_s_setprio(1);
#pragma unroll
            for (int df = 0; df < 4; df++) {
                const int vrow = df * 16 + lr;
                const int vcol = (kc * 4 + lg) ^ ((vrow & 3) | ((vrow >> 1) & 4));
                const bf16x8 vfr = *reinterpret_cast<const bf16x8*>(Vl + vrow * 64 + vcol * 8);
                o[df] = __builtin_amdgcn_mfma_f32_16x16x32_bf16(vfr, pfr, o[df], 0, 0, 0);
            }
            __builtin_amdgcn_s_setprio(0);
        }
        __builtin_amdgcn_s_barrier();   // all waves done reading buf[cur] before t+1 overwrites it
    }

    // epilogue: reduce partial l across the 4 lane-groups, write O^T -> AO
    const int b = bh >> 4, h = bh & 15;
    float lt = l_;
    lt += __shfl_xor(lt, 16, 64);
    lt += __shfl_xor(lt, 32, 64);
    const float rinv = 1.f / lt;
    const int q = qbase + lr;
#pragma unroll
    for (int df = 0; df < 4; df++) {
        us4 pk;
        pk.x = f2bf(o[df][0] * rinv); pk.y = f2bf(o[df][1] * rinv);
        pk.z = f2bf(o[df][2] * rinv); pk.w = f2bf(o[df][3] * rinv);
        *reinterpret_cast<us4*>(AO + (size_t)(b * 1024 + q) * 1024 + h * 64 + df * 16 + lg * 4) = pk;
    }
}

// ---------------- GEMM2: out = AO @ proj_w^T + proj_b (fp32 out) ----------------
__global__ __launch_bounds__(256) void gemm_proj_kernel(
        const unsigned short* __restrict__ A, const unsigned short* __restrict__ Bw,
        const float* __restrict__ bias, float* __restrict__ out) {
    __shared__ __align__(16) unsigned short As[128 * 32];
    __shared__ __align__(16) unsigned short Bs[128 * 32];
    const int tid = threadIdx.x;
    const int lane = tid & 63;
    const int wv = tid >> 6;
    const int wr = wv >> 1, wc = wv & 1;
    const int tm = blockIdx.y, tn = blockIdx.x;
    const int lr = lane & 15;

    f32x4 acc[4][4];
#pragma unroll
    for (int i = 0; i < 4; i++)
#pragma unroll
        for (int j = 0; j < 4; j++)
#pragma unroll
            for (int q = 0; q < 4; q++) acc[i][j][q] = 0.f;

    gemm_mainloop(A, Bw, As, Bs, tm, tn, acc);

#pragma unroll
    for (int i = 0; i < 4; i++)
#pragma unroll
        for (int j = 0; j < 4; j++)
#pragma unroll
            for (int r = 0; r < 4; r++) {
                const int row = tm * 128 + wr * 64 + i * 16 + (lane >> 4) * 4 + r;
                const int col = tn * 128 + wc * 64 + j * 16 + lr;
                out[(size_t)row * 1024 + col] = acc[i][j][r] + bias[col];
            }
}

extern "C" void kernel_launch(void* const* d_in, const int* in_sizes, int n_in,
                              void* d_out, int out_size, void* d_ws, size_t ws_size,
                              hipStream_t stream) {
    const float* x      = (const float*)d_in[0];
    const float* cosT   = (const float*)d_in[1];
    const float* sinT   = (const float*)d_in[2];
    const float* qkv_w  = (const float*)d_in[3];
    const float* qkv_b  = (const float*)d_in[4];
    const float* proj_w = (const float*)d_in[5];
    const float* proj_b = (const float*)d_in[6];
    float* out = (float*)d_out;

    char* ws = (char*)d_ws;
    unsigned short* xb    = (unsigned short*)(ws);                 // 8 MB  [4096][1024]
    unsigned short* wqkv  = (unsigned short*)(ws + (8u << 20));    // 6 MB  [3072][1024]
    unsigned short* wproj = (unsigned short*)(ws + (14u << 20));   // 2 MB  [1024][1024]
    unsigned short* Qb    = (unsigned short*)(ws + (16u << 20));   // 8 MB  [64][1024][64]
    unsigned short* Kb    = (unsigned short*)(ws + (24u << 20));   // 8 MB  [64][1024][64]
    unsigned short* Vt    = (unsigned short*)(ws + (32u << 20));   // 8 MB  [64][64][1024]
    unsigned short* AO    = (unsigned short*)(ws + (40u << 20));   // 8 MB  [4096][1024]

    cvt_kernel<<<2048, 256, 0, stream>>>(x, xb, 4096 * 1024);
    cvt_kernel<<<2048, 256, 0, stream>>>(qkv_w, wqkv, 3072 * 1024);
    cvt_kernel<<<1024, 256, 0, stream>>>(proj_w, wproj, 1024 * 1024);
    gemm_qkv_kernel<<<dim3(24, 32), 256, 0, stream>>>(xb, wqkv, qkv_b, cosT, sinT, Qb, Kb, Vt);
    attn_kernel<<<dim3(64, 16), 256, 0, stream>>>(Qb, Kb, Vt, AO);
    gemm_proj_kernel<<<dim3(8, 32), 256, 0, stream>>>(AO, wproj, proj_b, out);
}